// Round 7
// baseline (183.591 us; speedup 1.0000x reference)
//
#include <hip/hip_runtime.h>

typedef __attribute__((ext_vector_type(8))) short short8;
typedef __attribute__((ext_vector_type(4))) float f32x4;

#define KFC   131072   // 128*32*32
#define NCLS  1000

__device__ __forceinline__ unsigned short f2bf(float f) {
  union { float f; unsigned u; } v; v.f = f;
  unsigned r = v.u + 0x7FFFu + ((v.u >> 16) & 1u);   // RNE
  return (unsigned short)(r >> 16);
}

// ---------------------------------------------------------------------------
// conv1: x[64,3,128,128] fp32 -> y[64,64,64,64] bf16 NHWC (b,ph,pw,c)
// ---------------------------------------------------------------------------
__global__ __launch_bounds__(256) void conv1_kernel(
    const float* __restrict__ x, const float* __restrict__ w1,
    const float* __restrict__ b1, unsigned short* __restrict__ y) {
  __shared__ float tile[3][34][20];
  const int t = threadIdx.x;
  const int blk = blockIdx.x;                 // b*32 + ty*8 + tx
  const int tx = blk & 7, ty = (blk >> 3) & 3, b = blk >> 5;
  const int ih0 = ty * 32 - 1, iw0 = tx * 16 - 1;

  for (int i = t; i < 3 * 34 * 20; i += 256) {
    int ci = i / 680, rem = i - ci * 680;
    int r = rem / 20, s = rem - r * 20;
    int ih = ih0 + r, iw = iw0 + s;
    bool ok = (s < 18) && ((unsigned)ih < 128u) && ((unsigned)iw < 128u);
    tile[ci][r][s] = ok ? x[(b * 3 + ci) * 16384 + (ih << 7) + iw] : 0.f;
  }
  __syncthreads();

  const int c = t & 63, quad = t >> 6;
  const int qy = quad >> 1, qx = quad & 1;

  float wr[27];
#pragma unroll
  for (int k = 0; k < 27; ++k) wr[k] = w1[c * 27 + k];
  const float bias = b1[c];

  for (int pr = 0; pr < 8; ++pr) {
    float acc0[8], acc1[8];
#pragma unroll
    for (int i = 0; i < 8; ++i) { acc0[i] = 0.f; acc1[i] = 0.f; }

    const int r0 = qy * 16 + 2 * pr;
#pragma unroll
    for (int ci = 0; ci < 3; ++ci) {
#pragma unroll
      for (int r = 0; r < 4; ++r) {
        float rv[12];
        {
          const float* rp = &tile[ci][r0 + r][qx * 8];
#pragma unroll
          for (int v4 = 0; v4 < 3; ++v4) {
            float4 v = *(const float4*)(rp + v4 * 4);
            rv[v4 * 4 + 0] = v.x; rv[v4 * 4 + 1] = v.y;
            rv[v4 * 4 + 2] = v.z; rv[v4 * 4 + 3] = v.w;
          }
        }
        if (r < 3) {
#pragma unroll
          for (int kw = 0; kw < 3; ++kw) {
            float wt = wr[ci * 9 + r * 3 + kw];
#pragma unroll
            for (int w = 0; w < 8; ++w) acc0[w] += rv[w + kw] * wt;
          }
        }
        if (r >= 1) {
#pragma unroll
          for (int kw = 0; kw < 3; ++kw) {
            float wt = wr[ci * 9 + (r - 1) * 3 + kw];
#pragma unroll
            for (int w = 0; w < 8; ++w) acc1[w] += rv[w + kw] * wt;
          }
        }
      }
    }

    const int ph = ty * 16 + qy * 8 + pr;
    const int pwb = tx * 8 + qx * 4;
    unsigned short* dst = y + ((((size_t)b << 6) + ph) << 12) + ((size_t)pwb << 6) + c;
#pragma unroll
    for (int pw = 0; pw < 4; ++pw) {
      float m = fmaxf(fmaxf(acc0[2 * pw], acc0[2 * pw + 1]),
                      fmaxf(acc1[2 * pw], acc1[2 * pw + 1]));
      m = fmaxf(m + bias, 0.f);
      dst[(size_t)pw << 6] = f2bf(m);
    }
  }
}

// ---------------------------------------------------------------------------
// weight reorder for conv2: Bprep[((cg*9+pos)*128 + o)*32 + c] = bf16(w2[o][(cg*32+c)*9 + pos])
// ---------------------------------------------------------------------------
__global__ __launch_bounds__(256) void prep_w2(
    const float* __restrict__ w2, short* __restrict__ Bp) {
  int i = blockIdx.x * 256 + threadIdx.x;   // 73728 total
  int c = i & 31, o = (i >> 5) & 127, pp = i >> 12;
  int cg = pp / 9, pos = pp - cg * 9;
  Bp[i] = (short)f2bf(w2[o * 576 + (cg * 32 + c) * 9 + pos]);
}

// ---------------------------------------------------------------------------
// conv2 implicit-GEMM MFMA: y[64,64,64,64] bf16 NHWC -> A[64,131072] bf16 (flat [128,32,32])
// block: b x (4x4 grid of 16x16 conv tiles). 512 thr = 8 waves in 4M x 2N.
// ---------------------------------------------------------------------------
__global__ __launch_bounds__(512) void conv2_mfma(
    const short* __restrict__ yin, const short* __restrict__ Bp,
    const float* __restrict__ b2, unsigned int* __restrict__ A32) {
  __shared__ short tile[324 * 40];
  const int t = threadIdx.x;
  const int blk = blockIdx.x;
  const int tx = blk & 3, ty = (blk >> 2) & 3, b = blk >> 4;
  const int w = t >> 6, lane = t & 63;
  const int wm = w & 3, wn = w >> 2;          // 4M x 2N wave grid
  const int l15 = lane & 15, lg = lane >> 4;

  f32x4 acc[4][4];
#pragma unroll
  for (int m = 0; m < 4; ++m)
#pragma unroll
    for (int n = 0; n < 4; ++n) acc[m][n] = (f32x4){0.f, 0.f, 0.f, 0.f};

  const int ih0 = ty * 16 - 1, iw0 = tx * 16 - 1;

#pragma unroll
  for (int cg = 0; cg < 2; ++cg) {
    __syncthreads();
    for (int i = t; i < 324 * 4; i += 512) {
      int p = i >> 2, q = i & 3;
      int sy = p / 18, sx = p - sy * 18;
      int ih = ih0 + sy, iw = iw0 + sx;
      short8 v = (short8){0, 0, 0, 0, 0, 0, 0, 0};
      if (((unsigned)ih < 64u) && ((unsigned)iw < 64u))
        v = *(const short8*)(yin + ((((size_t)b << 6) + ih) << 12) + ((size_t)iw << 6) + cg * 32 + q * 8);
      *(short8*)&tile[p * 40 + q * 8] = v;
    }
    __syncthreads();

    const int py0 = wm * 4;
#pragma unroll
    for (int pos = 0; pos < 9; ++pos) {
      const int kh = pos / 3, kw = pos % 3;
      short8 bf[4];
#pragma unroll
      for (int n = 0; n < 4; ++n)
        bf[n] = *(const short8*)(Bp + ((((cg * 9 + pos) << 7) + (wn * 4 + n) * 16 + l15) << 5) + (lg << 3));
      short8 af[4];
#pragma unroll
      for (int m = 0; m < 4; ++m) {
        int sy = py0 + m + kh, sx = l15 + kw;
        af[m] = *(const short8*)&tile[(sy * 18 + sx) * 40 + lg * 8];
      }
#pragma unroll
      for (int n = 0; n < 4; ++n)
#pragma unroll
        for (int m = 0; m < 4; ++m)
          acc[m][n] = __builtin_amdgcn_mfma_f32_16x16x32_bf16(af[m], bf[n], acc[m][n], 0, 0, 0);
    }
  }

  const size_t bbase = ((size_t)b << 16);   // u32 units
#pragma unroll
  for (int n = 0; n < 4; ++n) {
    const int o = (wn * 4 + n) * 16 + l15;
    const float bias = b2[o];
#pragma unroll
    for (int mp = 0; mp < 2; ++mp) {
      const int prow = ty * 8 + wm * 2 + mp;
      float v0 = fmaxf(fmaxf(acc[2 * mp][n][0], acc[2 * mp][n][1]),
                       fmaxf(acc[2 * mp + 1][n][0], acc[2 * mp + 1][n][1]));
      float v1 = fmaxf(fmaxf(acc[2 * mp][n][2], acc[2 * mp][n][3]),
                       fmaxf(acc[2 * mp + 1][n][2], acc[2 * mp + 1][n][3]));
      v0 = fmaxf(v0 + bias, 0.f);
      v1 = fmaxf(v1 + bias, 0.f);
      unsigned pk = (unsigned)f2bf(v0) | ((unsigned)f2bf(v1) << 16);
      A32[bbase + (size_t)o * 512 + prow * 16 + tx * 4 + lg] = pk;
    }
  }
}

// ---------------------------------------------------------------------------
// fc1 MFMA (BW-bound): grid 1024 = 256 kc x 4 nt; K-chunk 512 (4 iters of 128).
// 4 blocks/CU resident -> 4 waves/SIMD; W stream overlaps across blocks.
// ---------------------------------------------------------------------------
__global__ __launch_bounds__(256) void fc1_mfma(
    const unsigned short* __restrict__ A, const float* __restrict__ W,
    float* __restrict__ P) {
  __shared__ short Wl[64 * 136];
  __shared__ short Al[64 * 136];
  const int t = threadIdx.x;
  const int kc = blockIdx.x >> 2, nt = blockIdx.x & 3;
  const int w = t >> 6, lane = t & 63;
  const int l15 = lane & 15, lg = lane >> 4;
  const int wm = w >> 1, wn = w & 1;

  const int row = t >> 2, q = t & 3;
  const float* wsrc = W + (size_t)(nt * 64 + row) * KFC + kc * 512 + q * 32;
  const unsigned short* asrc = A + (size_t)row * KFC + kc * 512 + q * 32;

  f32x4 acc[2][2];
#pragma unroll
  for (int i = 0; i < 2; ++i)
#pragma unroll
    for (int j = 0; j < 2; ++j) acc[i][j] = (f32x4){0.f, 0.f, 0.f, 0.f};

  f32x4 wreg[8]; short8 areg[4];
#pragma unroll
  for (int i = 0; i < 8; ++i) wreg[i] = *(const f32x4*)(wsrc + i * 4);
#pragma unroll
  for (int i = 0; i < 4; ++i) areg[i] = *(const short8*)(asrc + i * 8);

  for (int it = 0; it < 4; ++it) {
    __syncthreads();
    {
      unsigned* wd = (unsigned*)&Wl[row * 136 + q * 32];
#pragma unroll
      for (int i = 0; i < 8; ++i) {
        f32x4 v = wreg[i];
        wd[i * 2 + 0] = (unsigned)f2bf(v[0]) | ((unsigned)f2bf(v[1]) << 16);
        wd[i * 2 + 1] = (unsigned)f2bf(v[2]) | ((unsigned)f2bf(v[3]) << 16);
      }
      short8* ad = (short8*)&Al[row * 136 + q * 32];
#pragma unroll
      for (int i = 0; i < 4; ++i) ad[i] = areg[i];
    }
    __syncthreads();
    if (it < 3) {
      const float* wp = wsrc + (it + 1) * 128;
      const unsigned short* ap = asrc + (it + 1) * 128;
#pragma unroll
      for (int i = 0; i < 8; ++i) wreg[i] = *(const f32x4*)(wp + i * 4);
#pragma unroll
      for (int i = 0; i < 4; ++i) areg[i] = *(const short8*)(ap + i * 8);
    }
#pragma unroll
    for (int ks = 0; ks < 4; ++ks) {
      short8 af0 = *(const short8*)&Al[(wm * 32 + l15) * 136 + ks * 32 + lg * 8];
      short8 af1 = *(const short8*)&Al[(wm * 32 + 16 + l15) * 136 + ks * 32 + lg * 8];
      short8 bf0 = *(const short8*)&Wl[(wn * 32 + l15) * 136 + ks * 32 + lg * 8];
      short8 bf1 = *(const short8*)&Wl[(wn * 32 + 16 + l15) * 136 + ks * 32 + lg * 8];
      acc[0][0] = __builtin_amdgcn_mfma_f32_16x16x32_bf16(af0, bf0, acc[0][0], 0, 0, 0);
      acc[0][1] = __builtin_amdgcn_mfma_f32_16x16x32_bf16(af0, bf1, acc[0][1], 0, 0, 0);
      acc[1][0] = __builtin_amdgcn_mfma_f32_16x16x32_bf16(af1, bf0, acc[1][0], 0, 0, 0);
      acc[1][1] = __builtin_amdgcn_mfma_f32_16x16x32_bf16(af1, bf1, acc[1][1], 0, 0, 0);
    }
  }

  float* dst = P + (size_t)kc * 16384;
#pragma unroll
  for (int mf = 0; mf < 2; ++mf)
#pragma unroll
    for (int nf = 0; nf < 2; ++nf)
#pragma unroll
      for (int j = 0; j < 4; ++j) {
        int brow = wm * 32 + mf * 16 + lg * 4 + j;
        int o = nt * 64 + wn * 32 + nf * 16 + l15;
        dst[brow * 256 + o] = acc[mf][nf][j];
      }
}

// fc1 partial reduce + bias + relu -> Y[64,256]
__global__ __launch_bounds__(256) void fc1_reduce_kernel(
    const float* __restrict__ P, const float* __restrict__ fb1,
    float* __restrict__ Y) {
  int idx = blockIdx.x * 256 + threadIdx.x;   // b*256 + o
  float s0 = 0, s1 = 0, s2 = 0, s3 = 0;
  for (int p = 0; p < 256; p += 4) {
    s0 += P[(size_t)(p + 0) * 16384 + idx];
    s1 += P[(size_t)(p + 1) * 16384 + idx];
    s2 += P[(size_t)(p + 2) * 16384 + idx];
    s3 += P[(size_t)(p + 3) * 16384 + idx];
  }
  float s = (s0 + s1) + (s2 + s3);
  Y[idx] = fmaxf(s + fb1[idx & 255], 0.f);
}

// fc2: out[64,1000] = Y[64,256] @ W2[1000,256]^T + b2
__global__ __launch_bounds__(256) void fc2_kernel(
    const float* __restrict__ Y, const float* __restrict__ W2,
    const float* __restrict__ b2, float* __restrict__ out) {
  int tid = blockIdx.x * 256 + threadIdx.x;
  if (tid >= 64 * NCLS) return;
  int b = tid / NCLS, n = tid - b * NCLS;
  const float4* yv = (const float4*)(Y + b * 256);
  const float4* wv = (const float4*)(W2 + n * 256);
  float acc = 0.f;
#pragma unroll 8
  for (int f = 0; f < 64; ++f) {
    float4 a = yv[f], w = wv[f];
    acc += a.x * w.x + a.y * w.y + a.z * w.z + a.w * w.w;
  }
  out[tid] = acc + b2[n];
}

// ---------------------------------------------------------------------------
extern "C" void kernel_launch(void* const* d_in, const int* in_sizes, int n_in,
                              void* d_out, int out_size, void* d_ws, size_t ws_size,
                              hipStream_t stream) {
  const float* x   = (const float*)d_in[0];
  const float* w1  = (const float*)d_in[1];
  const float* b1  = (const float*)d_in[2];
  const float* w2  = (const float*)d_in[3];
  const float* b2  = (const float*)d_in[4];
  const float* fw1 = (const float*)d_in[5];
  const float* fb1 = (const float*)d_in[6];
  const float* fw2 = (const float*)d_in[7];
  const float* fb2 = (const float*)d_in[8];
  float* out = (float*)d_out;

  unsigned short* Y1 = (unsigned short*)d_ws;              // conv1 out bf16 NHWC [16777216]
  unsigned short* A16 = Y1 + 16777216;                     // conv2 out bf16 [8388608]
  short* Bp = (short*)(A16 + 8388608);                     // conv2 weights bf16 [73728]
  float* P  = (float*)(Bp + 73728);                        // fc1 partials [256*16384]
  float* Yf = P + 4194304;                                 // fc1 out [16384]

  prep_w2<<<288, 256, 0, stream>>>(w2, Bp);
  conv1_kernel<<<2048, 256, 0, stream>>>(x, w1, b1, Y1);
  conv2_mfma<<<1024, 512, 0, stream>>>((const short*)Y1, Bp, b2, (unsigned int*)A16);
  fc1_mfma<<<1024, 256, 0, stream>>>(A16, fw1, P);
  fc1_reduce_kernel<<<64, 256, 0, stream>>>(P, fb1, Yf);
  fc2_kernel<<<250, 256, 0, stream>>>(Yf, fw2, fb2, out);
}

// Round 8
// 157.427 us; speedup vs baseline: 1.1662x; 1.1662x over previous
//
#include <hip/hip_runtime.h>

typedef __attribute__((ext_vector_type(8))) short short8;
typedef __attribute__((ext_vector_type(4))) float f32x4;

#define KFC   131072   // 128*32*32
#define NCLS  1000

__device__ __forceinline__ unsigned short f2bf(float f) {
  union { float f; unsigned u; } v; v.f = f;
  unsigned r = v.u + 0x7FFFu + ((v.u >> 16) & 1u);   // RNE
  return (unsigned short)(r >> 16);
}

// ---------------------------------------------------------------------------
// conv1: x[64,3,128,128] fp32 -> y[64,64,64,64] bf16 NHWC (b,ph,pw,c)
// ---------------------------------------------------------------------------
__global__ __launch_bounds__(256) void conv1_kernel(
    const float* __restrict__ x, const float* __restrict__ w1,
    const float* __restrict__ b1, unsigned short* __restrict__ y) {
  __shared__ float tile[3][34][20];
  const int t = threadIdx.x;
  const int blk = blockIdx.x;                 // b*32 + ty*8 + tx
  const int tx = blk & 7, ty = (blk >> 3) & 3, b = blk >> 5;
  const int ih0 = ty * 32 - 1, iw0 = tx * 16 - 1;

  for (int i = t; i < 3 * 34 * 20; i += 256) {
    int ci = i / 680, rem = i - ci * 680;
    int r = rem / 20, s = rem - r * 20;
    int ih = ih0 + r, iw = iw0 + s;
    bool ok = (s < 18) && ((unsigned)ih < 128u) && ((unsigned)iw < 128u);
    tile[ci][r][s] = ok ? x[(b * 3 + ci) * 16384 + (ih << 7) + iw] : 0.f;
  }
  __syncthreads();

  const int c = t & 63, quad = t >> 6;
  const int qy = quad >> 1, qx = quad & 1;

  float wr[27];
#pragma unroll
  for (int k = 0; k < 27; ++k) wr[k] = w1[c * 27 + k];
  const float bias = b1[c];

  for (int pr = 0; pr < 8; ++pr) {
    float acc0[8], acc1[8];
#pragma unroll
    for (int i = 0; i < 8; ++i) { acc0[i] = 0.f; acc1[i] = 0.f; }

    const int r0 = qy * 16 + 2 * pr;
#pragma unroll
    for (int ci = 0; ci < 3; ++ci) {
#pragma unroll
      for (int r = 0; r < 4; ++r) {
        float rv[12];
        {
          const float* rp = &tile[ci][r0 + r][qx * 8];
#pragma unroll
          for (int v4 = 0; v4 < 3; ++v4) {
            float4 v = *(const float4*)(rp + v4 * 4);
            rv[v4 * 4 + 0] = v.x; rv[v4 * 4 + 1] = v.y;
            rv[v4 * 4 + 2] = v.z; rv[v4 * 4 + 3] = v.w;
          }
        }
        if (r < 3) {
#pragma unroll
          for (int kw = 0; kw < 3; ++kw) {
            float wt = wr[ci * 9 + r * 3 + kw];
#pragma unroll
            for (int w = 0; w < 8; ++w) acc0[w] += rv[w + kw] * wt;
          }
        }
        if (r >= 1) {
#pragma unroll
          for (int kw = 0; kw < 3; ++kw) {
            float wt = wr[ci * 9 + (r - 1) * 3 + kw];
#pragma unroll
            for (int w = 0; w < 8; ++w) acc1[w] += rv[w + kw] * wt;
          }
        }
      }
    }

    const int ph = ty * 16 + qy * 8 + pr;
    const int pwb = tx * 8 + qx * 4;
    unsigned short* dst = y + ((((size_t)b << 6) + ph) << 12) + ((size_t)pwb << 6) + c;
#pragma unroll
    for (int pw = 0; pw < 4; ++pw) {
      float m = fmaxf(fmaxf(acc0[2 * pw], acc0[2 * pw + 1]),
                      fmaxf(acc1[2 * pw], acc1[2 * pw + 1]));
      m = fmaxf(m + bias, 0.f);
      dst[(size_t)pw << 6] = f2bf(m);
    }
  }
}

// ---------------------------------------------------------------------------
// weight reorder for conv2: Bprep[((cg*9+pos)*128 + o)*32 + c] = bf16(w2[o][(cg*32+c)*9 + pos])
// ---------------------------------------------------------------------------
__global__ __launch_bounds__(256) void prep_w2(
    const float* __restrict__ w2, short* __restrict__ Bp) {
  int i = blockIdx.x * 256 + threadIdx.x;   // 73728 total
  int c = i & 31, o = (i >> 5) & 127, pp = i >> 12;
  int cg = pp / 9, pos = pp - cg * 9;
  Bp[i] = (short)f2bf(w2[o * 576 + (cg * 32 + c) * 9 + pos]);
}

// ---------------------------------------------------------------------------
// conv2 implicit-GEMM MFMA: y[64,64,64,64] bf16 NHWC -> A[64,131072] bf16 (flat [128,32,32])
// block: b x (4x4 grid of 16x16 conv tiles). 512 thr = 8 waves in 2M x 4N:
// wave = M 128 px (8 m-frags, rows wm*8..+7) x N 32 o (2 n-frags).
// Halves bf-L2 traffic (590->295 MB) and af-ds traffic vs 4Mx2N round-6 shape.
// ---------------------------------------------------------------------------
__global__ __launch_bounds__(512) void conv2_mfma(
    const short* __restrict__ yin, const short* __restrict__ Bp,
    const float* __restrict__ b2, unsigned int* __restrict__ A32) {
  __shared__ short tile[324 * 40];
  const int t = threadIdx.x;
  const int blk = blockIdx.x;
  const int tx = blk & 3, ty = (blk >> 2) & 3, b = blk >> 4;
  const int w = t >> 6, lane = t & 63;
  const int wm = w & 1, wn = w >> 1;          // 2M x 4N wave grid
  const int l15 = lane & 15, lg = lane >> 4;

  f32x4 acc[8][2];
#pragma unroll
  for (int m = 0; m < 8; ++m)
#pragma unroll
    for (int n = 0; n < 2; ++n) acc[m][n] = (f32x4){0.f, 0.f, 0.f, 0.f};

  const int ih0 = ty * 16 - 1, iw0 = tx * 16 - 1;

#pragma unroll
  for (int cg = 0; cg < 2; ++cg) {
    __syncthreads();
    for (int i = t; i < 324 * 4; i += 512) {
      int p = i >> 2, q = i & 3;
      int sy = p / 18, sx = p - sy * 18;
      int ih = ih0 + sy, iw = iw0 + sx;
      short8 v = (short8){0, 0, 0, 0, 0, 0, 0, 0};
      if (((unsigned)ih < 64u) && ((unsigned)iw < 64u))
        v = *(const short8*)(yin + ((((size_t)b << 6) + ih) << 12) + ((size_t)iw << 6) + cg * 32 + q * 8);
      *(short8*)&tile[p * 40 + q * 8] = v;
    }
    __syncthreads();

    const int py0 = wm * 8;
#pragma unroll
    for (int pos = 0; pos < 9; ++pos) {
      const int kh = pos / 3, kw = pos % 3;
      short8 bf[2];
#pragma unroll
      for (int n = 0; n < 2; ++n)
        bf[n] = *(const short8*)(Bp + ((((cg * 9 + pos) << 7) + (wn * 2 + n) * 16 + l15) << 5) + (lg << 3));
#pragma unroll
      for (int half = 0; half < 2; ++half) {
        short8 af[4];
#pragma unroll
        for (int m = 0; m < 4; ++m) {
          int sy = py0 + half * 4 + m + kh, sx = l15 + kw;
          af[m] = *(const short8*)&tile[(sy * 18 + sx) * 40 + lg * 8];
        }
#pragma unroll
        for (int n = 0; n < 2; ++n)
#pragma unroll
          for (int m = 0; m < 4; ++m)
            acc[half * 4 + m][n] = __builtin_amdgcn_mfma_f32_16x16x32_bf16(af[m], bf[n], acc[half * 4 + m][n], 0, 0, 0);
      }
    }
  }

  // epilogue: bias + relu + 2x2 pool; acc frag a covers tile row py0+a, x = lg*4+reg
  const size_t bbase = ((size_t)b << 16);   // u32 units
#pragma unroll
  for (int n = 0; n < 2; ++n) {
    const int o = (wn * 2 + n) * 16 + l15;
    const float bias = b2[o];
#pragma unroll
    for (int mp = 0; mp < 4; ++mp) {
      const int prow = ty * 8 + wm * 4 + mp;
      float v0 = fmaxf(fmaxf(acc[2 * mp][n][0], acc[2 * mp][n][1]),
                       fmaxf(acc[2 * mp + 1][n][0], acc[2 * mp + 1][n][1]));
      float v1 = fmaxf(fmaxf(acc[2 * mp][n][2], acc[2 * mp][n][3]),
                       fmaxf(acc[2 * mp + 1][n][2], acc[2 * mp + 1][n][3]));
      v0 = fmaxf(v0 + bias, 0.f);
      v1 = fmaxf(v1 + bias, 0.f);
      unsigned pk = (unsigned)f2bf(v0) | ((unsigned)f2bf(v1) << 16);
      A32[bbase + (size_t)o * 512 + prow * 16 + tx * 4 + lg] = pk;
    }
  }
}

// ---------------------------------------------------------------------------
// fc1 MFMA (BW-bound): grid 1024 = 256 kc x 4 nt; K-chunk 512 (4 iters of 128).
// ---------------------------------------------------------------------------
__global__ __launch_bounds__(256) void fc1_mfma(
    const unsigned short* __restrict__ A, const float* __restrict__ W,
    float* __restrict__ P) {
  __shared__ short Wl[64 * 136];
  __shared__ short Al[64 * 136];
  const int t = threadIdx.x;
  const int kc = blockIdx.x >> 2, nt = blockIdx.x & 3;
  const int w = t >> 6, lane = t & 63;
  const int l15 = lane & 15, lg = lane >> 4;
  const int wm = w >> 1, wn = w & 1;

  const int row = t >> 2, q = t & 3;
  const float* wsrc = W + (size_t)(nt * 64 + row) * KFC + kc * 512 + q * 32;
  const unsigned short* asrc = A + (size_t)row * KFC + kc * 512 + q * 32;

  f32x4 acc[2][2];
#pragma unroll
  for (int i = 0; i < 2; ++i)
#pragma unroll
    for (int j = 0; j < 2; ++j) acc[i][j] = (f32x4){0.f, 0.f, 0.f, 0.f};

  f32x4 wreg[8]; short8 areg[4];
#pragma unroll
  for (int i = 0; i < 8; ++i) wreg[i] = *(const f32x4*)(wsrc + i * 4);
#pragma unroll
  for (int i = 0; i < 4; ++i) areg[i] = *(const short8*)(asrc + i * 8);

  for (int it = 0; it < 4; ++it) {
    __syncthreads();
    {
      unsigned* wd = (unsigned*)&Wl[row * 136 + q * 32];
#pragma unroll
      for (int i = 0; i < 8; ++i) {
        f32x4 v = wreg[i];
        wd[i * 2 + 0] = (unsigned)f2bf(v[0]) | ((unsigned)f2bf(v[1]) << 16);
        wd[i * 2 + 1] = (unsigned)f2bf(v[2]) | ((unsigned)f2bf(v[3]) << 16);
      }
      short8* ad = (short8*)&Al[row * 136 + q * 32];
#pragma unroll
      for (int i = 0; i < 4; ++i) ad[i] = areg[i];
    }
    __syncthreads();
    if (it < 3) {
      const float* wp = wsrc + (it + 1) * 128;
      const unsigned short* ap = asrc + (it + 1) * 128;
#pragma unroll
      for (int i = 0; i < 8; ++i) wreg[i] = *(const f32x4*)(wp + i * 4);
#pragma unroll
      for (int i = 0; i < 4; ++i) areg[i] = *(const short8*)(ap + i * 8);
    }
#pragma unroll
    for (int ks = 0; ks < 4; ++ks) {
      short8 af0 = *(const short8*)&Al[(wm * 32 + l15) * 136 + ks * 32 + lg * 8];
      short8 af1 = *(const short8*)&Al[(wm * 32 + 16 + l15) * 136 + ks * 32 + lg * 8];
      short8 bf0 = *(const short8*)&Wl[(wn * 32 + l15) * 136 + ks * 32 + lg * 8];
      short8 bf1 = *(const short8*)&Wl[(wn * 32 + 16 + l15) * 136 + ks * 32 + lg * 8];
      acc[0][0] = __builtin_amdgcn_mfma_f32_16x16x32_bf16(af0, bf0, acc[0][0], 0, 0, 0);
      acc[0][1] = __builtin_amdgcn_mfma_f32_16x16x32_bf16(af0, bf1, acc[0][1], 0, 0, 0);
      acc[1][0] = __builtin_amdgcn_mfma_f32_16x16x32_bf16(af1, bf0, acc[1][0], 0, 0, 0);
      acc[1][1] = __builtin_amdgcn_mfma_f32_16x16x32_bf16(af1, bf1, acc[1][1], 0, 0, 0);
    }
  }

  float* dst = P + (size_t)kc * 16384;
#pragma unroll
  for (int mf = 0; mf < 2; ++mf)
#pragma unroll
    for (int nf = 0; nf < 2; ++nf)
#pragma unroll
      for (int j = 0; j < 4; ++j) {
        int brow = wm * 32 + mf * 16 + lg * 4 + j;
        int o = nt * 64 + wn * 32 + nf * 16 + l15;
        dst[brow * 256 + o] = acc[mf][nf][j];
      }
}

// fc1 partial reduce + bias + relu -> Y[64,256]. 256 blocks, coalesced:
// lane = output idx (64/block), 4 p-groups of 64 partials, LDS combine.
__global__ __launch_bounds__(256) void fc1_reduce_kernel(
    const float* __restrict__ P, const float* __restrict__ fb1,
    float* __restrict__ Y) {
  __shared__ float red[4][64];
  const int t = threadIdx.x;
  const int iq = t & 63, pg = t >> 6;
  const int gidx = blockIdx.x * 64 + iq;
  const float* p0 = P + (size_t)(pg * 64) * 16384 + gidx;
  float s0 = 0, s1 = 0, s2 = 0, s3 = 0;
#pragma unroll
  for (int p = 0; p < 64; p += 4) {
    s0 += p0[(size_t)(p + 0) * 16384];
    s1 += p0[(size_t)(p + 1) * 16384];
    s2 += p0[(size_t)(p + 2) * 16384];
    s3 += p0[(size_t)(p + 3) * 16384];
  }
  red[pg][iq] = (s0 + s1) + (s2 + s3);
  __syncthreads();
  if (pg == 0) {
    float tot = (red[0][iq] + red[1][iq]) + (red[2][iq] + red[3][iq]);
    Y[gidx] = fmaxf(tot + fb1[gidx & 255], 0.f);
  }
}

// fc2: out[64,1000] = Y[64,256] @ W2[1000,256]^T + b2
__global__ __launch_bounds__(256) void fc2_kernel(
    const float* __restrict__ Y, const float* __restrict__ W2,
    const float* __restrict__ b2, float* __restrict__ out) {
  int tid = blockIdx.x * 256 + threadIdx.x;
  if (tid >= 64 * NCLS) return;
  int b = tid / NCLS, n = tid - b * NCLS;
  const float4* yv = (const float4*)(Y + b * 256);
  const float4* wv = (const float4*)(W2 + n * 256);
  float acc = 0.f;
#pragma unroll 8
  for (int f = 0; f < 64; ++f) {
    float4 a = yv[f], w = wv[f];
    acc += a.x * w.x + a.y * w.y + a.z * w.z + a.w * w.w;
  }
  out[tid] = acc + b2[n];
}

// ---------------------------------------------------------------------------
extern "C" void kernel_launch(void* const* d_in, const int* in_sizes, int n_in,
                              void* d_out, int out_size, void* d_ws, size_t ws_size,
                              hipStream_t stream) {
  const float* x   = (const float*)d_in[0];
  const float* w1  = (const float*)d_in[1];
  const float* b1  = (const float*)d_in[2];
  const float* w2  = (const float*)d_in[3];
  const float* b2  = (const float*)d_in[4];
  const float* fw1 = (const float*)d_in[5];
  const float* fb1 = (const float*)d_in[6];
  const float* fw2 = (const float*)d_in[7];
  const float* fb2 = (const float*)d_in[8];
  float* out = (float*)d_out;

  unsigned short* Y1 = (unsigned short*)d_ws;              // conv1 out bf16 NHWC [16777216]
  unsigned short* A16 = Y1 + 16777216;                     // conv2 out bf16 [8388608]
  short* Bp = (short*)(A16 + 8388608);                     // conv2 weights bf16 [73728]
  float* P  = (float*)(Bp + 73728);                        // fc1 partials [256*16384]
  float* Yf = P + 4194304;                                 // fc1 out [16384]

  prep_w2<<<288, 256, 0, stream>>>(w2, Bp);
  conv1_kernel<<<2048, 256, 0, stream>>>(x, w1, b1, Y1);
  conv2_mfma<<<1024, 512, 0, stream>>>((const short*)Y1, Bp, b2, (unsigned int*)A16);
  fc1_mfma<<<1024, 256, 0, stream>>>(A16, fw1, P);
  fc1_reduce_kernel<<<256, 256, 0, stream>>>(P, fb1, Yf);
  fc2_kernel<<<250, 256, 0, stream>>>(Yf, fw2, fb2, out);
}